// Round 10
// baseline (158.349 us; speedup 1.0000x reference)
//
#include <hip/hip_runtime.h>

#define BB 16
#define CC 2
#define TT 1000
#define FF 257
#define NBC (BB * CC)                               // 32
#define NCHAIN (NBC * FF)                           // 8224
#define RES_ELEMS ((size_t)BB * CC * TT * FF * 2)   // 16,448,000

#define TC 10                    // timesteps per tile
#define KC (TT / TC)             // 100 chunks per bc (exact)
#define ROWF (FF * 2)            // 514 floats per t-row
#define TILEF (TC * ROWF)        // 5140 floats = 20560 B per tile
#define TILE4 (TILEF / 4)        // 1285 float4
#define NTHR 320                 // 5 waves; LDS 20.6 KB -> 6 blocks/CU
#define NBLK (NBC * KC)          // 3200 blocks
#define STATE_WORDS (KC * NCHAIN)                   // 822,400
#define STATE_BYTES ((size_t)STATE_WORDS * 4)       // 3.29 MB

// Single-pass scan with decoupled lookback (rocPRIM-style):
// - virtual block rank from a global counter => predecessors always started
//   (rank of (bc,k-1) = rank-32), no dispatch-order deadlock.
// - per-(chain,chunk) state word: float value with status packed in the 2 low
//   mantissa bits (0=empty, 1=aggregate e_k, 2=inclusive S_k); <=3-ulp value
//   perturbation, single relaxed 32-bit atomic per publish/consume.
// - combine is affine with uniform per-chunk decay p10 = om^10:
//   S_init(k) = sum_j p10^(k-1-j)*e_j + p10^(k-1-m)*S_incl(m).

__device__ __forceinline__ unsigned pk(unsigned st, float v) {
    return (__float_as_uint(v) & ~3u) | st;
}

__global__ __launch_bounds__(NTHR, 8) void fnorm_fused(
    const float* __restrict__ input,
    const float* __restrict__ weights,
    const float* __restrict__ bias,
    const float* __restrict__ alpha,
    const float* __restrict__ s1,
    float* __restrict__ out,
    unsigned* __restrict__ state,
    unsigned* __restrict__ vcnt)
{
    __shared__ float lds[TILEF];
    __shared__ unsigned sh_rank;

    if (threadIdx.x == 0)
        sh_rank = __hip_atomic_fetch_add(vcnt, 1u, __ATOMIC_RELAXED,
                                         __HIP_MEMORY_SCOPE_AGENT);
    __syncthreads();
    const int r  = (int)sh_rank;
    const int bc = r & (NBC - 1);       // 32 bc per k-wavefront
    const int k  = r >> 5;              // chunk index 0..99

    // Sequential tile load (proven 4+ TB/s pattern).
    const size_t base = (size_t)bc * (TT * ROWF) + (size_t)k * TILEF;
    const float4* __restrict__ src = (const float4*)(input + base);
    for (int i = threadIdx.x; i < TILE4; i += NTHR)
        ((float4*)lds)[i] = src[i];
    __syncthreads();

    const int f = threadIdx.x;
    const int chain = bc * FF + f;
    float av = 0.f, om = 0.f, w = 0.f, bi = 0.f, e = 0.f, p10 = 0.f;
    if (f < FF) {
        const int cf = (bc & 1) * FF + f;
        av = 1.0f / (1.0f + __expf(-alpha[cf]));
        om = 1.0f - av;
        w  = weights[cf];
        bi = bias[cf];
        float s = 0.f;
        #pragma unroll
        for (int t = 0; t < TC; ++t) {
            float2 v = ((const float2*)lds)[t * FF + f];
            s = fmaf(fmaf(v.x, v.x, v.y * v.y), av, s * om);
        }
        e = s;
        const float om2 = om * om, om4 = om2 * om2, om8 = om4 * om4;
        p10 = om8 * om2;
    }

    float S = 0.f;                       // init state for this chunk
    if (k == 0) {
        if (f < FF) {
            S = s1[chain];
            __hip_atomic_store(&state[chain], pk(2u, fmaf(S, p10, e)),
                               __ATOMIC_RELAXED, __HIP_MEMORY_SCOPE_AGENT);
        }
    } else if (f < FF) {
        if (k < KC - 1)                  // k==KC-1 has no successors
            __hip_atomic_store(&state[k * NCHAIN + chain], pk(1u, e),
                               __ATOMIC_RELAXED, __HIP_MEMORY_SCOPE_AGENT);
        // Per-thread lookback, 4-wide batched loads (independent addresses).
        float E = 0.f, P = 1.f;
        int j = k - 1;
        bool done = false;
        while (!done) {
            unsigned wv[4];
            const int nb = (j + 1 < 4) ? (j + 1) : 4;
            #pragma unroll
            for (int l = 0; l < 4; ++l)
                if (l < nb)
                    wv[l] = __hip_atomic_load(&state[(j - l) * NCHAIN + chain],
                                              __ATOMIC_RELAXED,
                                              __HIP_MEMORY_SCOPE_AGENT);
            #pragma unroll
            for (int l = 0; l < 4; ++l) {
                if (l < nb && !done) {
                    unsigned v = wv[l];
                    while ((v & 3u) == 0u) {          // spin: pred started by rank order
                        __builtin_amdgcn_s_sleep(1);
                        v = __hip_atomic_load(&state[(j - l) * NCHAIN + chain],
                                              __ATOMIC_RELAXED,
                                              __HIP_MEMORY_SCOPE_AGENT);
                    }
                    E = fmaf(P, __uint_as_float(v & ~3u), E);
                    if ((v & 3u) == 2u) done = true;  // hit an inclusive: finished
                    else                P *= p10;
                }
            }
            j -= nb;
            if (j < 0) done = true;      // unreachable: k==0 publishes status 2
        }
        S = E;
        if (k < KC - 1)                  // upgrade to inclusive for successors
            __hip_atomic_store(&state[k * NCHAIN + chain], pk(2u, fmaf(S, p10, e)),
                               __ATOMIC_RELAXED, __HIP_MEMORY_SCOPE_AGENT);
    }

    // Rescan + transform in LDS.
    if (f < FF) {
        float s = S;
        #pragma unroll
        for (int t = 0; t < TC; ++t) {
            float2 v = ((const float2*)lds)[t * FF + f];
            s = fmaf(fmaf(v.x, v.x, v.y * v.y), av, s * om);
            const float inv = __frsqrt_rn(s + 1e-16f) * w;
            float2 y;
            y.x = fmaf(v.x, inv, bi);
            y.y = fmaf(v.y, inv, bi);
            ((float2*)lds)[t * FF + f] = y;
        }
        if (k == KC - 1)
            out[RES_ELEMS + (size_t)chain] = s;       // s_last (exact sequential)
    }
    __syncthreads();

    // Sequential tile store.
    float4* __restrict__ dst = (float4*)(out + base);
    for (int i = threadIdx.x; i < TILE4; i += NTHR)
        dst[i] = ((const float4*)lds)[i];
}

extern "C" void kernel_launch(void* const* d_in, const int* in_sizes, int n_in,
                              void* d_out, int out_size, void* d_ws, size_t ws_size,
                              hipStream_t stream) {
    const float* input   = (const float*)d_in[0];
    const float* weights = (const float*)d_in[1];
    const float* bias    = (const float*)d_in[2];
    const float* alpha   = (const float*)d_in[3];
    const float* s1      = (const float*)d_in[4];
    float* out = (float*)d_out;

    unsigned* state = (unsigned*)d_ws;                       // 3.29 MB
    unsigned* vcnt  = (unsigned*)((char*)d_ws + STATE_BYTES);

    // Stream-ordered (graph-capture-legal) zeroing of state + rank counter.
    hipMemsetAsync(d_ws, 0, STATE_BYTES + 8, stream);
    hipLaunchKernelGGL(fnorm_fused, dim3(NBLK), dim3(NTHR), 0, stream,
                       input, weights, bias, alpha, s1, out, state, vcnt);
}